// Round 9
// baseline (197.793 us; speedup 1.0000x reference)
//
#include <hip/hip_runtime.h>

// Problem: y[b,l,o] = sum_{k,i} x[b, idx[l,k], i] * mask[k,i,o] + bias[o]
// B=4, L=10000, K=16, I=256, O=256  => gathered GEMM M=40000, N=256, KK=4096
#define Bdim 4
#define Ldim 10000
#define Kdim 16
#define Idim 256
#define Odim 256

typedef __attribute__((ext_vector_type(8))) __bf16 bf16x8;
typedef __attribute__((ext_vector_type(4))) float f32x4;

// ---------------- fused pre-pass ----------------
// blocks [0,2500): convert x fp32->bf16 (4096 floats per block: 256 thr x 16)
// blocks [2500,3012): pack mask into B-fragment order Wpk[c][lane][8],
//                     c = kb*32 + wid*8 + ks*4 + ni
__global__ __launch_bounds__(256)
void prepack(const float* __restrict__ x, const float* __restrict__ mask,
             __bf16* __restrict__ xb, __bf16* __restrict__ wpk)
{
    const int b = blockIdx.x;
    if (b < 2500) {
        const size_t base = ((size_t)b * 256 + threadIdx.x) * 16;
#pragma unroll
        for (int j = 0; j < 2; ++j) {
            const float4 f0 = *(const float4*)(x + base + j * 8);
            const float4 f1 = *(const float4*)(x + base + j * 8 + 4);
            bf16x8 v;
            v[0] = (__bf16)f0.x; v[1] = (__bf16)f0.y; v[2] = (__bf16)f0.z; v[3] = (__bf16)f0.w;
            v[4] = (__bf16)f1.x; v[5] = (__bf16)f1.y; v[6] = (__bf16)f1.z; v[7] = (__bf16)f1.w;
            *(bf16x8*)(xb + base + j * 8) = v;
        }
    } else {
        const int tg = (b - 2500) * 256 + threadIdx.x;    // 0..131071
        const int c  = tg >> 6;                            // chunk 0..2047
        const int ln = tg & 63;
        const int ni  = c & 3;
        const int ks  = (c >> 2) & 1;
        const int wid = (c >> 3) & 3;
        const int kb  = c >> 5;
        const int n   = wid * 64 + ni * 16 + (ln & 15);
        const int kk0 = kb * 64 + ks * 32 + (ln >> 4) * 8;
        bf16x8 v;
#pragma unroll
        for (int j = 0; j < 8; ++j)
            v[j] = (__bf16)mask[(size_t)(kk0 + j) * Odim + n];
        *(bf16x8*)(wpk + (size_t)tg * 8) = v;
    }
}

// ---------------- main GEMM: TL=20, fragment-major LDS, BK=128 ----------------
// R8 (BK=64) showed a ~2000cy fixed cost per barrier-step invariant to
// conflicts/depth/balance. This version halves the step count (32 steps of
// BK=128 = two W k-blocks) and doubles MFMA per step (80) to amortize it.
// W double-buffer has FIXED roles: wA = even kb (loaded mid-step for next
// step), wB = odd kb (loaded and consumed within the step).
// A staging mapping (128-wide rows): unit u = t + j*256 (j<5), r=u%80,
// p=u/80 -> 16-lane group = 16 consecutive rows x 16B = all 32 banks
// (R8-proven conflict-free pattern); part-major variant would be 16-way.
// Summation order over k unchanged -> numerics identical to R8.
#define TL 20          // l per block -> 500 blocks exact
#define BM 80          // = Bdim * TL
#define IDXS 17        // idx_lds k-stride (bank spread)

#define BARRIER() do { asm volatile("s_waitcnt lgkmcnt(0)" ::: "memory"); \
                       __builtin_amdgcn_s_barrier(); } while (0)

__global__ __launch_bounds__(256, 2)
void piconv_gemm(const __bf16* __restrict__ xb,
                 const int* __restrict__ idxT,
                 const __bf16* __restrict__ wpk,
                 const float* __restrict__ bias,
                 float* __restrict__ out)
{
    __shared__ __bf16 Alds[2][BM * 128];   // 2 x 20 KB, fragment-major
    __shared__ int    idx_lds[TL * IDXS];  // 20 l x 16 k, stride 17

    const int t    = threadIdx.x;
    const int l0   = blockIdx.x * TL;
    const int lane = t & 63;
    const int wid  = t >> 6;               // n-quadrant
    const int q    = lane >> 4;
    const int r16  = lane & 15;

    // stage idx table: 320 entries -> [l][k] at stride 17
    {
        const int e0 = t;
        idx_lds[(e0 >> 4) * IDXS + (e0 & 15)] = idxT[l0 * Kdim + e0];
        if (t < 64) {
            const int e1 = t + 256;
            idx_lds[(e1 >> 4) * IDXS + (e1 & 15)] = idxT[l0 * Kdim + e1];
        }
    }

    // ---- staging constants: 5 units/thread, u = t + j*256, r=u%80, p=u/80 ----
    // LDS byte offset: frag f=(r>>4)*4+(p>>2); f*1024 + (p&3)*256 + (r&15)*16
    int    alt_[5], dsb_[5], go_[5];
    size_t abase_[5];
#pragma unroll
    for (int j = 0; j < 5; ++j) {
        const int u = t + j * 256;
        const int r = u % 80;
        const int p = u / 80;              // 0..15
        alt_[j]   = r % TL;
        abase_[j] = ((size_t)(r / TL) * Ldim) << 8;
        dsb_[j]   = ((r >> 4) * 4 + (p >> 2)) * 1024 + (p & 3) * 256 + (r & 15) * 16;
        go_[j]    = p * 8;                 // element offset within 128-k row half
    }

    // W fragment base: + kb*16384 + (ks2*4+ni)*512
    const __bf16* wbase = wpk + ((size_t)(wid * 8) << 9) + lane * 8;

    f32x4  acc[5][4] = {};
    bf16x8 aR[5];
    bf16x8 wA[8], wB[8];                   // wA: even kb, wB: odd kb (fixed roles)

    __syncthreads();                       // idx table ready

    // prologue: gather A(step 0) -> aR, wA = W(kb 0)
#pragma unroll
    for (int j = 0; j < 5; ++j) {
        const int iv = idx_lds[alt_[j] * IDXS];
        aR[j] = *(const bf16x8*)(xb + abase_[j] + (((size_t)iv) << 8) + go_[j]);
    }
#pragma unroll
    for (int j = 0; j < 8; ++j)
        wA[j] = *(const bf16x8*)(wbase + j * 512);

    // ---- main loop: 31 full steps + peeled step 31 ----
    for (int S = 0; S < 31; ++S) {
        char* db = (char*)&Alds[S & 1][0];
#pragma unroll
        for (int j = 0; j < 5; ++j)
            *(bf16x8*)(db + dsb_[j]) = aR[j];
        BARRIER();
        // prefetch A(S+1): step T covers k in [T*128, T*128+128), idx group T>>1
        {
            const int kn  = (S + 1) >> 1;
            const int iob = ((S + 1) & 1) << 7;
#pragma unroll
            for (int j = 0; j < 5; ++j) {
                const int iv = idx_lds[alt_[j] * IDXS + kn];
                aR[j] = *(const bf16x8*)(xb + abase_[j] + (((size_t)iv) << 8) + iob + go_[j]);
            }
        }
        // wB = W(2S+1), consumed this step (ks 2,3)
        {
            const __bf16* wq = wbase + ((size_t)(2 * S + 1)) * 16384;
#pragma unroll
            for (int j = 0; j < 8; ++j)
                wB[j] = *(const bf16x8*)(wq + j * 512);
        }
        // first half: ks 0,1 with wA (kb = 2S)
#pragma unroll
        for (int ks = 0; ks < 2; ++ks) {
            bf16x8 af[5];
#pragma unroll
            for (int mi = 0; mi < 5; ++mi)
                af[mi] = *(const bf16x8*)(db + (mi * 4 + ks) * 1024 + lane * 16);
#pragma unroll
            for (int mi = 0; mi < 5; ++mi)
#pragma unroll
                for (int ni = 0; ni < 4; ++ni)
                    acc[mi][ni] = __builtin_amdgcn_mfma_f32_16x16x32_bf16(
                        af[mi], wA[ks * 4 + ni], acc[mi][ni], 0, 0, 0);
        }
        // wA = W(2S+2), consumed next step
        {
            const __bf16* wq = wbase + ((size_t)(2 * S + 2)) * 16384;
#pragma unroll
            for (int j = 0; j < 8; ++j)
                wA[j] = *(const bf16x8*)(wq + j * 512);
        }
        // second half: ks 2,3 with wB (kb = 2S+1)
#pragma unroll
        for (int ks = 2; ks < 4; ++ks) {
            bf16x8 af[5];
#pragma unroll
            for (int mi = 0; mi < 5; ++mi)
                af[mi] = *(const bf16x8*)(db + (mi * 4 + ks) * 1024 + lane * 16);
#pragma unroll
            for (int mi = 0; mi < 5; ++mi)
#pragma unroll
                for (int ni = 0; ni < 4; ++ni)
                    acc[mi][ni] = __builtin_amdgcn_mfma_f32_16x16x32_bf16(
                        af[mi], wB[(ks - 2) * 4 + ni], acc[mi][ni], 0, 0, 0);
        }
    }
    // peeled step S=31: no A/wA prefetch; wA holds W(62), load wB=W(63)
    {
        char* db = (char*)&Alds[1][0];
#pragma unroll
        for (int j = 0; j < 5; ++j)
            *(bf16x8*)(db + dsb_[j]) = aR[j];
        BARRIER();
        {
            const __bf16* wq = wbase + ((size_t)63) * 16384;
#pragma unroll
            for (int j = 0; j < 8; ++j)
                wB[j] = *(const bf16x8*)(wq + j * 512);
        }
#pragma unroll
        for (int ks = 0; ks < 2; ++ks) {
            bf16x8 af[5];
#pragma unroll
            for (int mi = 0; mi < 5; ++mi)
                af[mi] = *(const bf16x8*)(db + (mi * 4 + ks) * 1024 + lane * 16);
#pragma unroll
            for (int mi = 0; mi < 5; ++mi)
#pragma unroll
                for (int ni = 0; ni < 4; ++ni)
                    acc[mi][ni] = __builtin_amdgcn_mfma_f32_16x16x32_bf16(
                        af[mi], wA[ks * 4 + ni], acc[mi][ni], 0, 0, 0);
        }
#pragma unroll
        for (int ks = 2; ks < 4; ++ks) {
            bf16x8 af[5];
#pragma unroll
            for (int mi = 0; mi < 5; ++mi)
                af[mi] = *(const bf16x8*)(db + (mi * 4 + ks) * 1024 + lane * 16);
#pragma unroll
            for (int mi = 0; mi < 5; ++mi)
#pragma unroll
                for (int ni = 0; ni < 4; ++ni)
                    acc[mi][ni] = __builtin_amdgcn_mfma_f32_16x16x32_bf16(
                        af[mi], wB[(ks - 2) * 4 + ni], acc[mi][ni], 0, 0, 0);
        }
    }

    // ---- epilogue: C/D layout col=lane&15, row=(lane>>4)*4+reg ----
    float bv[4];
#pragma unroll
    for (int ni = 0; ni < 4; ++ni)
        bv[ni] = bias[wid * 64 + ni * 16 + r16];
#pragma unroll
    for (int mi = 0; mi < 5; ++mi) {
#pragma unroll
        for (int rr = 0; rr < 4; ++rr) {
            const int r  = mi * 16 + q * 4 + rr;   // 0..79
            const int ab = r / TL;
            const int al = r % TL;
            float* dst = out + (((size_t)(ab * Ldim + l0 + al)) << 8) + wid * 64 + r16;
#pragma unroll
            for (int ni = 0; ni < 4; ++ni)
                dst[ni * 16] = acc[mi][ni][rr] + bv[ni];
        }
    }
}

// ---------------- fallback (no-ws path) ----------------
#define FTL 32
#define FBN 128
#define FLDA 72
__global__ __launch_bounds__(256)
void piconv_fallback(const float* __restrict__ x,
                     const int* __restrict__ idxT,
                     const float* __restrict__ mask,
                     const float* __restrict__ bias,
                     float* __restrict__ out)
{
    __shared__ __bf16 Alds[128 * FLDA];
    __shared__ __bf16 Wlds[FBN * FLDA];
    const int t  = threadIdx.x;
    const int l0 = blockIdx.x * FTL;
    const int n0 = blockIdx.y * FBN;
    const int lane = t & 63;
    const int wid  = t >> 6;
    const int wm   = wid >> 1;
    const int wn   = wid & 1;
    const int q    = lane >> 4;
    const int r16  = lane & 15;
    f32x4 acc[4][4] = {};
    const int am    = t >> 1;
    const int ahalf = t & 1;
    const int alt   = am & 31;
    const int abb   = am >> 5;
    const int al    = l0 + alt;
    const bool avalid = (al < Ldim);
    for (int kb = 0; kb < 64; ++kb) {
        {
            const int ksl = kb >> 2;
            const int i0  = ((kb & 3) << 6) + (ahalf << 5);
            const int idx = avalid ? idxT[al * Kdim + ksl] : 0;
            const float* src = x + (((size_t)(abb * Ldim + idx)) << 8) + i0;
#pragma unroll
            for (int j = 0; j < 4; ++j) {
                const float4 f0 = *(const float4*)(src + j * 8);
                const float4 f1 = *(const float4*)(src + j * 8 + 4);
                bf16x8 v;
                v[0] = (__bf16)f0.x; v[1] = (__bf16)f0.y; v[2] = (__bf16)f0.z; v[3] = (__bf16)f0.w;
                v[4] = (__bf16)f1.x; v[5] = (__bf16)f1.y; v[6] = (__bf16)f1.z; v[7] = (__bf16)f1.w;
                *(bf16x8*)&Alds[am * FLDA + (ahalf << 5) + j * 8] = v;
            }
        }
        {
#pragma unroll
            for (int it = 0; it < 4; ++it) {
                const int pair = t + it * 256;
                const int n    = pair & 127;
                const int g    = pair >> 7;
                const float* src = mask + (((size_t)(kb * 64 + g * 8)) << 8) + n0 + n;
                bf16x8 v;
#pragma unroll
                for (int j = 0; j < 8; ++j)
                    v[j] = (__bf16)src[(size_t)j << 8];
                *(bf16x8*)&Wlds[n * FLDA + g * 8] = v;
            }
        }
        __syncthreads();
#pragma unroll
        for (int ks = 0; ks < 2; ++ks) {
            bf16x8 af[4], bfr[4];
#pragma unroll
            for (int mi = 0; mi < 4; ++mi)
                af[mi] = *(bf16x8*)&Alds[(wm * 64 + mi * 16 + r16) * FLDA + ks * 32 + q * 8];
#pragma unroll
            for (int ni = 0; ni < 4; ++ni)
                bfr[ni] = *(bf16x8*)&Wlds[(wn * 64 + ni * 16 + r16) * FLDA + ks * 32 + q * 8];
#pragma unroll
            for (int mi = 0; mi < 4; ++mi)
#pragma unroll
                for (int ni = 0; ni < 4; ++ni)
                    acc[mi][ni] = __builtin_amdgcn_mfma_f32_16x16x32_bf16(
                        af[mi], bfr[ni], acc[mi][ni], 0, 0, 0);
        }
        __syncthreads();
    }
    float bv[4];
#pragma unroll
    for (int ni = 0; ni < 4; ++ni)
        bv[ni] = bias[n0 + wn * 64 + ni * 16 + r16];
#pragma unroll
    for (int mi = 0; mi < 4; ++mi) {
        const int mrow = wm * 64 + mi * 16 + q * 4;
#pragma unroll
        for (int rr = 0; rr < 4; ++rr) {
            const int m  = mrow + rr;
            const int lt = m & 31;
            const int bb = m >> 5;
            const int l  = l0 + lt;
            if (l < Ldim) {
                float* dst = out + (((size_t)(bb * Ldim + l)) << 8) + n0 + wn * 64 + r16;
#pragma unroll
                for (int ni = 0; ni < 4; ++ni)
                    dst[ni * 16] = acc[mi][ni][rr] + bv[ni];
            }
        }
    }
}

extern "C" void kernel_launch(void* const* d_in, const int* in_sizes, int n_in,
                              void* d_out, int out_size, void* d_ws, size_t ws_size,
                              hipStream_t stream) {
    const float* x    = (const float*)d_in[0];
    const int*   idx  = (const int*)d_in[1];
    const float* mask = (const float*)d_in[2];
    const float* bias = (const float*)d_in[3];
    float* out = (float*)d_out;

    const size_t xb_bytes = (size_t)Bdim * Ldim * Idim * 2;   // 20,480,000
    const size_t wp_bytes = (size_t)Kdim * Idim * Odim * 2;   //  2,097,152

    if (ws_size >= xb_bytes + wp_bytes) {
        __bf16* xb  = (__bf16*)d_ws;
        __bf16* wpk = (__bf16*)((char*)d_ws + xb_bytes);
        // 2500 x-convert blocks (2500*256*16 = 10,240,000 floats, exact) + 512 pack blocks
        prepack<<<2500 + 512, 256, 0, stream>>>(x, mask, xb, wpk);
        piconv_gemm<<<Ldim / TL, 256, 0, stream>>>(xb, idx, wpk, bias, out);
    } else {
        dim3 grid((Ldim + FTL - 1) / FTL, Odim / FBN, 1);
        piconv_fallback<<<grid, 256, 0, stream>>>(x, idx, mask, bias, out);
    }
}

// Round 10
// 180.821 us; speedup vs baseline: 1.0939x; 1.0939x over previous
//
#include <hip/hip_runtime.h>

// Problem: y[b,l,o] = sum_{k,i} x[b, idx[l,k], i] * mask[k,i,o] + bias[o]
// B=4, L=10000, K=16, I=256, O=256  => gathered GEMM M=40000, N=256, KK=4096
#define Bdim 4
#define Ldim 10000
#define Kdim 16
#define Idim 256
#define Odim 256

typedef __attribute__((ext_vector_type(8))) __bf16 bf16x8;
typedef __attribute__((ext_vector_type(4))) float f32x4;

// ---------------- fused pre-pass ----------------
// blocks [0,2500): convert x fp32->bf16 (4096 floats per block: 256 thr x 16)
// blocks [2500,3012): pack mask into B-fragment order Wpk[c][lane][8],
//                     c = kb*32 + wid*8 + ks*4 + ni
__global__ __launch_bounds__(256)
void prepack(const float* __restrict__ x, const float* __restrict__ mask,
             __bf16* __restrict__ xb, __bf16* __restrict__ wpk)
{
    const int b = blockIdx.x;
    if (b < 2500) {
        const size_t base = ((size_t)b * 256 + threadIdx.x) * 16;
#pragma unroll
        for (int j = 0; j < 2; ++j) {
            const float4 f0 = *(const float4*)(x + base + j * 8);
            const float4 f1 = *(const float4*)(x + base + j * 8 + 4);
            bf16x8 v;
            v[0] = (__bf16)f0.x; v[1] = (__bf16)f0.y; v[2] = (__bf16)f0.z; v[3] = (__bf16)f0.w;
            v[4] = (__bf16)f1.x; v[5] = (__bf16)f1.y; v[6] = (__bf16)f1.z; v[7] = (__bf16)f1.w;
            *(bf16x8*)(xb + base + j * 8) = v;
        }
    } else {
        const int tg = (b - 2500) * 256 + threadIdx.x;    // 0..131071
        const int c  = tg >> 6;                            // chunk 0..2047
        const int ln = tg & 63;
        const int ni  = c & 3;
        const int ks  = (c >> 2) & 1;
        const int wid = (c >> 3) & 3;
        const int kb  = c >> 5;
        const int n   = wid * 64 + ni * 16 + (ln & 15);
        const int kk0 = kb * 64 + ks * 32 + (ln >> 4) * 8;
        bf16x8 v;
#pragma unroll
        for (int j = 0; j < 8; ++j)
            v[j] = (__bf16)mask[(size_t)(kk0 + j) * Odim + n];
        *(bf16x8*)(wpk + (size_t)tg * 8) = v;
    }
}

// ------- main GEMM: R8 skeleton + quad-coalesced gather + swz LDS + setprio -------
// Changes vs R8 (95us, MfmaUtil 37, conflicts 5K):
//  (a) A-gather remapped so each aligned lane-QUAD reads 4x16B = one 64B line
//      of one x-row (wave = 16 rows x 64B) -> ~4x fewer TA line requests than
//      R8's 16B-scattered pattern. Unit u = (t>>2)+64j (j<3, j=2 only t<128):
//      row r=u%80, half h=u/80 (= ks), part p=t&3 (= k-quad).
//  (b) fragment-interior XOR swizzle  off ^= p<<5  (bank-visible bits 5,6):
//      without it, quad writes are same-bank (256B part stride is bank-
//      invisible). Write side: slots (p*16 + (r^2p)) all distinct. Read side:
//      lane L (g=L>>4, rr=L&15) reads (g*256+rr*16)^(g<<5) -> 64 distinct
//      16B slots. Conflict-free both sides (verify: SQ_LDS_BANK_CONFLICT).
//  (c) T5 setprio(1) around MFMA cluster: 2 independent barrier groups/CU
//      (m191 condition) -> scheduler can favor the MFMA-phase wave.
#define TL 20          // l per block -> 500 blocks exact
#define BM 80          // = Bdim * TL
#define IDXS 17        // idx_lds k-stride (bank spread)

#define BARRIER() do { asm volatile("s_waitcnt lgkmcnt(0)" ::: "memory"); \
                       __builtin_amdgcn_s_barrier(); } while (0)

__global__ __launch_bounds__(256, 2)
void piconv_gemm(const __bf16* __restrict__ xb,
                 const int* __restrict__ idxT,
                 const __bf16* __restrict__ wpk,
                 const float* __restrict__ bias,
                 float* __restrict__ out)
{
    __shared__ __bf16 Alds[2][BM * 64];    // 2 x 10.0 KB, fragment-major+swz
    __shared__ int    idx_lds[TL * IDXS];  // 20 l x 16 k, stride 17

    const int t    = threadIdx.x;
    const int l0   = blockIdx.x * TL;
    const int lane = t & 63;
    const int wid  = t >> 6;               // n-quadrant
    const int q    = lane >> 4;
    const int r16  = lane & 15;

    // stage idx table: 320 entries -> [l][k] at stride 17
    {
        const int e0 = t;
        idx_lds[(e0 >> 4) * IDXS + (e0 & 15)] = idxT[l0 * Kdim + e0];
        if (t < 64) {
            const int e1 = t + 256;
            idx_lds[(e1 >> 4) * IDXS + (e1 & 15)] = idxT[l0 * Kdim + e1];
        }
    }

    // ---- staging constants: 3 quad-units/thread (j=2 only for t<128) ----
    // unit u = (t>>2) + 64*j: row r=u%80, half h=u/80 (=ks), part p=t&3.
    // global elem off (within step's 128B k-slice): h*32 + p*8
    // LDS byte off: f=(r>>4)*2+h; f*1024 + ((p*256 + (r&15)*16) ^ (p<<5))
    const int p4 = t & 3;
    int    alt_[3], dsb_[3], goff_[3];
    size_t abase_[3];
#pragma unroll
    for (int j = 0; j < 3; ++j) {
        const int u = (t >> 2) + 64 * j;   // valid iff u<160
        const int r = u % 80;
        const int h = u / 80;
        alt_[j]   = r % TL;
        abase_[j] = ((size_t)(r / TL) * Ldim) << 8;
        dsb_[j]   = ((r >> 4) * 2 + h) * 1024
                  + ((p4 * 256 + (r & 15) * 16) ^ (p4 << 5));
        goff_[j]  = h * 32 + p4 * 8;
    }
    const bool j2 = (t < 128);
    // read-side swizzled lane offset within a 1KB fragment
    const int aoff = ((lane >> 4) * 256 + r16 * 16) ^ ((lane >> 4) << 5);

    // W fragment base: + kb*16384 + (ks*4+ni)*512
    const __bf16* wbase = wpk + ((size_t)(wid * 8) << 9) + lane * 8;

    f32x4  acc[5][4] = {};
    bf16x8 aR[3];
    bf16x8 wA[8], wB[8];

    __syncthreads();                       // idx table ready

    // prologue: gather A(0) -> aR, W(0) -> wA
    {
        const int iv0 = idx_lds[alt_[0] * IDXS];
        const int iv1 = idx_lds[alt_[1] * IDXS];
        aR[0] = *(const bf16x8*)(xb + abase_[0] + (((size_t)iv0) << 8) + goff_[0]);
        aR[1] = *(const bf16x8*)(xb + abase_[1] + (((size_t)iv1) << 8) + goff_[1]);
        if (j2) {
            const int iv2 = idx_lds[alt_[2] * IDXS];
            aR[2] = *(const bf16x8*)(xb + abase_[2] + (((size_t)iv2) << 8) + goff_[2]);
        }
#pragma unroll
        for (int j = 0; j < 8; ++j)
            wA[j] = *(const bf16x8*)(wbase + j * 512);
    }

#define STEP(S, WCUR, WNXT, PFA, PFW)                                           \
    {                                                                           \
        char* db = (char*)&Alds[(S) & 1][0];                                    \
        *(bf16x8*)(db + dsb_[0]) = aR[0];                                       \
        *(bf16x8*)(db + dsb_[1]) = aR[1];                                       \
        if (j2) *(bf16x8*)(db + dsb_[2]) = aR[2];                               \
        BARRIER();                                                              \
        if (PFA) {  /* gather A(S+1) */                                         \
            const int T   = (S) + 1;                                            \
            const int kn  = T >> 2;                                             \
            const int iob = (T & 3) << 6;                                       \
            const int iv0 = idx_lds[alt_[0] * IDXS + kn];                       \
            const int iv1 = idx_lds[alt_[1] * IDXS + kn];                       \
            aR[0] = *(const bf16x8*)(xb + abase_[0] + (((size_t)iv0) << 8) + iob + goff_[0]); \
            aR[1] = *(const bf16x8*)(xb + abase_[1] + (((size_t)iv1) << 8) + iob + goff_[1]); \
            if (j2) {                                                           \
                const int iv2 = idx_lds[alt_[2] * IDXS + kn];                   \
                aR[2] = *(const bf16x8*)(xb + abase_[2] + (((size_t)iv2) << 8) + iob + goff_[2]); \
            }                                                                   \
        }                                                                       \
        if (PFW) {  /* W(S+1) */                                                \
            const __bf16* wq = wbase + ((size_t)((S) + 1)) * 16384;             \
            _Pragma("unroll")                                                   \
            for (int j = 0; j < 8; ++j)                                         \
                WNXT[j] = *(const bf16x8*)(wq + j * 512);                       \
        }                                                                       \
        __builtin_amdgcn_s_setprio(1);                                          \
        _Pragma("unroll")                                                       \
        for (int ks = 0; ks < 2; ++ks) {                                        \
            bf16x8 af[5];                                                       \
            _Pragma("unroll")                                                   \
            for (int mi = 0; mi < 5; ++mi)                                      \
                af[mi] = *(const bf16x8*)(db + (mi * 2 + ks) * 1024 + aoff);    \
            _Pragma("unroll")                                                   \
            for (int mi = 0; mi < 5; ++mi)                                      \
                _Pragma("unroll")                                               \
                for (int ni = 0; ni < 4; ++ni)                                  \
                    acc[mi][ni] = __builtin_amdgcn_mfma_f32_16x16x32_bf16(      \
                        af[mi], WCUR[ks * 4 + ni], acc[mi][ni], 0, 0, 0);       \
        }                                                                       \
        __builtin_amdgcn_s_setprio(0);                                          \
    }

    for (int s2 = 0; s2 < 31; ++s2) {
        STEP(2 * s2,     wA, wB, true, true)
        STEP(2 * s2 + 1, wB, wA, true, true)
    }
    // tail: step 62 still prefetches A(63) (1-ahead pipeline); step 63 none
    STEP(62, wA, wB, true,  true)
    STEP(63, wB, wA, false, false)
#undef STEP

    // ---- epilogue: C/D layout col=lane&15, row=(lane>>4)*4+reg ----
    float bv[4];
#pragma unroll
    for (int ni = 0; ni < 4; ++ni)
        bv[ni] = bias[wid * 64 + ni * 16 + r16];
#pragma unroll
    for (int mi = 0; mi < 5; ++mi) {
#pragma unroll
        for (int rr = 0; rr < 4; ++rr) {
            const int r  = mi * 16 + q * 4 + rr;   // 0..79
            const int ab = r / TL;
            const int al = r % TL;
            float* dst = out + (((size_t)(ab * Ldim + l0 + al)) << 8) + wid * 64 + r16;
#pragma unroll
            for (int ni = 0; ni < 4; ++ni)
                dst[ni * 16] = acc[mi][ni][rr] + bv[ni];
        }
    }
}

// ---------------- fallback (no-ws path) ----------------
#define FTL 32
#define FBN 128
#define FLDA 72
__global__ __launch_bounds__(256)
void piconv_fallback(const float* __restrict__ x,
                     const int* __restrict__ idxT,
                     const float* __restrict__ mask,
                     const float* __restrict__ bias,
                     float* __restrict__ out)
{
    __shared__ __bf16 Alds[128 * FLDA];
    __shared__ __bf16 Wlds[FBN * FLDA];
    const int t  = threadIdx.x;
    const int l0 = blockIdx.x * FTL;
    const int n0 = blockIdx.y * FBN;
    const int lane = t & 63;
    const int wid  = t >> 6;
    const int wm   = wid >> 1;
    const int wn   = wid & 1;
    const int q    = lane >> 4;
    const int r16  = lane & 15;
    f32x4 acc[4][4] = {};
    const int am    = t >> 1;
    const int ahalf = t & 1;
    const int alt   = am & 31;
    const int abb   = am >> 5;
    const int al    = l0 + alt;
    const bool avalid = (al < Ldim);
    for (int kb = 0; kb < 64; ++kb) {
        {
            const int ksl = kb >> 2;
            const int i0  = ((kb & 3) << 6) + (ahalf << 5);
            const int idx = avalid ? idxT[al * Kdim + ksl] : 0;
            const float* src = x + (((size_t)(abb * Ldim + idx)) << 8) + i0;
#pragma unroll
            for (int j = 0; j < 4; ++j) {
                const float4 f0 = *(const float4*)(src + j * 8);
                const float4 f1 = *(const float4*)(src + j * 8 + 4);
                bf16x8 v;
                v[0] = (__bf16)f0.x; v[1] = (__bf16)f0.y; v[2] = (__bf16)f0.z; v[3] = (__bf16)f0.w;
                v[4] = (__bf16)f1.x; v[5] = (__bf16)f1.y; v[6] = (__bf16)f1.z; v[7] = (__bf16)f1.w;
                *(bf16x8*)&Alds[am * FLDA + (ahalf << 5) + j * 8] = v;
            }
        }
        {
#pragma unroll
            for (int it = 0; it < 4; ++it) {
                const int pair = t + it * 256;
                const int n    = pair & 127;
                const int g    = pair >> 7;
                const float* src = mask + (((size_t)(kb * 64 + g * 8)) << 8) + n0 + n;
                bf16x8 v;
#pragma unroll
                for (int j = 0; j < 8; ++j)
                    v[j] = (__bf16)src[(size_t)j << 8];
                *(bf16x8*)&Wlds[n * FLDA + g * 8] = v;
            }
        }
        __syncthreads();
#pragma unroll
        for (int ks = 0; ks < 2; ++ks) {
            bf16x8 af[4], bfr[4];
#pragma unroll
            for (int mi = 0; mi < 4; ++mi)
                af[mi] = *(bf16x8*)&Alds[(wm * 64 + mi * 16 + r16) * FLDA + ks * 32 + q * 8];
#pragma unroll
            for (int ni = 0; ni < 4; ++ni)
                bfr[ni] = *(bf16x8*)&Wlds[(wn * 64 + ni * 16 + r16) * FLDA + ks * 32 + q * 8];
#pragma unroll
            for (int mi = 0; mi < 4; ++mi)
#pragma unroll
                for (int ni = 0; ni < 4; ++ni)
                    acc[mi][ni] = __builtin_amdgcn_mfma_f32_16x16x32_bf16(
                        af[mi], bfr[ni], acc[mi][ni], 0, 0, 0);
        }
        __syncthreads();
    }
    float bv[4];
#pragma unroll
    for (int ni = 0; ni < 4; ++ni)
        bv[ni] = bias[n0 + wn * 64 + ni * 16 + r16];
#pragma unroll
    for (int mi = 0; mi < 4; ++mi) {
        const int mrow = wm * 64 + mi * 16 + q * 4;
#pragma unroll
        for (int rr = 0; rr < 4; ++rr) {
            const int m  = mrow + rr;
            const int lt = m & 31;
            const int bb = m >> 5;
            const int l  = l0 + lt;
            if (l < Ldim) {
                float* dst = out + (((size_t)(bb * Ldim + l)) << 8) + n0 + wn * 64 + r16;
#pragma unroll
                for (int ni = 0; ni < 4; ++ni)
                    dst[ni * 16] = acc[mi][ni][rr] + bv[ni];
            }
        }
    }
}

extern "C" void kernel_launch(void* const* d_in, const int* in_sizes, int n_in,
                              void* d_out, int out_size, void* d_ws, size_t ws_size,
                              hipStream_t stream) {
    const float* x    = (const float*)d_in[0];
    const int*   idx  = (const int*)d_in[1];
    const float* mask = (const float*)d_in[2];
    const float* bias = (const float*)d_in[3];
    float* out = (float*)d_out;

    const size_t xb_bytes = (size_t)Bdim * Ldim * Idim * 2;   // 20,480,000
    const size_t wp_bytes = (size_t)Kdim * Idim * Odim * 2;   //  2,097,152

    if (ws_size >= xb_bytes + wp_bytes) {
        __bf16* xb  = (__bf16*)d_ws;
        __bf16* wpk = (__bf16*)((char*)d_ws + xb_bytes);
        // 2500 x-convert blocks (2500*256*16 = 10,240,000 floats, exact) + 512 pack blocks
        prepack<<<2500 + 512, 256, 0, stream>>>(x, mask, xb, wpk);
        piconv_gemm<<<Ldim / TL, 256, 0, stream>>>(xb, idx, wpk, bias, out);
    } else {
        dim3 grid((Ldim + FTL - 1) / FTL, Odim / FBN, 1);
        piconv_fallback<<<grid, 256, 0, stream>>>(x, idx, mask, bias, out);
    }
}

// Round 11
// 177.601 us; speedup vs baseline: 1.1137x; 1.0181x over previous
//
#include <hip/hip_runtime.h>

// Problem: y[b,l,o] = sum_{k,i} x[b, idx[l,k], i] * mask[k,i,o] + bias[o]
// B=4, L=10000, K=16, I=256, O=256  => gathered GEMM M=40000, N=256, KK=4096
#define Bdim 4
#define Ldim 10000
#define Kdim 16
#define Idim 256
#define Odim 256

typedef __attribute__((ext_vector_type(8))) __bf16 bf16x8;
typedef __attribute__((ext_vector_type(4))) float f32x4;

// ---------------- fused pre-pass ----------------
// blocks [0,2500): convert x fp32->bf16 (4096 floats per block: 256 thr x 16)
// blocks [2500,3012): pack mask into B-fragment order Wpk[c][lane][8],
//                     c = kb*32 + wid*8 + ks*4 + ni
__global__ __launch_bounds__(256)
void prepack(const float* __restrict__ x, const float* __restrict__ mask,
             __bf16* __restrict__ xb, __bf16* __restrict__ wpk)
{
    const int b = blockIdx.x;
    if (b < 2500) {
        const size_t base = ((size_t)b * 256 + threadIdx.x) * 16;
#pragma unroll
        for (int j = 0; j < 2; ++j) {
            const float4 f0 = *(const float4*)(x + base + j * 8);
            const float4 f1 = *(const float4*)(x + base + j * 8 + 4);
            bf16x8 v;
            v[0] = (__bf16)f0.x; v[1] = (__bf16)f0.y; v[2] = (__bf16)f0.z; v[3] = (__bf16)f0.w;
            v[4] = (__bf16)f1.x; v[5] = (__bf16)f1.y; v[6] = (__bf16)f1.z; v[7] = (__bf16)f1.w;
            *(bf16x8*)(xb + base + j * 8) = v;
        }
    } else {
        const int tg = (b - 2500) * 256 + threadIdx.x;    // 0..131071
        const int c  = tg >> 6;                            // chunk 0..2047
        const int ln = tg & 63;
        const int ni  = c & 3;
        const int ks  = (c >> 2) & 1;
        const int wid = (c >> 3) & 3;
        const int kb  = c >> 5;
        const int n   = wid * 64 + ni * 16 + (ln & 15);
        const int kk0 = kb * 64 + ks * 32 + (ln >> 4) * 8;
        bf16x8 v;
#pragma unroll
        for (int j = 0; j < 8; ++j)
            v[j] = (__bf16)mask[(size_t)(kk0 + j) * Odim + n];
        *(bf16x8*)(wpk + (size_t)tg * 8) = v;
    }
}

// ------- main GEMM: R10 skeleton + 2-step-deep A prefetch -------
// R10 (93.2us, MfmaUtil 37.9): quad-coalesced gather (lane-quad = 64B line),
// p-XOR swizzled fragment-major LDS (conflicts ~5K), setprio on MFMA.
// This round: A-gather issued at step S is consumed (ds_write) at step S+2,
// not S+1 -> gather coverage doubles to ~2 MFMA clusters (~1550cy + step
// overhead >= worst-case miss latency), eliminating the vmcnt stall at the
// ds_write that heads the per-step serial chain. Two register slots
// (aR0 even steps, aR1 odd steps), +12 VGPR. Data order identical to R10.
#define TL 20          // l per block -> 500 blocks exact
#define BM 80          // = Bdim * TL
#define IDXS 17        // idx_lds k-stride (bank spread)

#define BARRIER() do { asm volatile("s_waitcnt lgkmcnt(0)" ::: "memory"); \
                       __builtin_amdgcn_s_barrier(); } while (0)

__global__ __launch_bounds__(256, 2)
void piconv_gemm(const __bf16* __restrict__ xb,
                 const int* __restrict__ idxT,
                 const __bf16* __restrict__ wpk,
                 const float* __restrict__ bias,
                 float* __restrict__ out)
{
    __shared__ __bf16 Alds[2][BM * 64];    // 2 x 10.0 KB, fragment-major+swz
    __shared__ int    idx_lds[TL * IDXS];  // 20 l x 16 k, stride 17

    const int t    = threadIdx.x;
    const int l0   = blockIdx.x * TL;
    const int lane = t & 63;
    const int wid  = t >> 6;               // n-quadrant
    const int q    = lane >> 4;
    const int r16  = lane & 15;

    // stage idx table: 320 entries -> [l][k] at stride 17
    {
        const int e0 = t;
        idx_lds[(e0 >> 4) * IDXS + (e0 & 15)] = idxT[l0 * Kdim + e0];
        if (t < 64) {
            const int e1 = t + 256;
            idx_lds[(e1 >> 4) * IDXS + (e1 & 15)] = idxT[l0 * Kdim + e1];
        }
    }

    // ---- staging constants: 3 quad-units/thread (j=2 only for t<128) ----
    // unit u = (t>>2) + 64*j: row r=u%80, half h=u/80 (=ks), part p=t&3.
    // global elem off (within step's 128B k-slice): h*32 + p*8
    // LDS byte off: f=(r>>4)*2+h; f*1024 + ((p*256 + (r&15)*16) ^ (p<<5))
    const int p4 = t & 3;
    int    alt_[3], dsb_[3], goff_[3];
    size_t abase_[3];
#pragma unroll
    for (int j = 0; j < 3; ++j) {
        const int u = (t >> 2) + 64 * j;   // valid iff u<160
        const int r = u % 80;
        const int h = u / 80;
        alt_[j]   = r % TL;
        abase_[j] = ((size_t)(r / TL) * Ldim) << 8;
        dsb_[j]   = ((r >> 4) * 2 + h) * 1024
                  + ((p4 * 256 + (r & 15) * 16) ^ (p4 << 5));
        goff_[j]  = h * 32 + p4 * 8;
    }
    const bool j2 = (t < 128);
    // read-side swizzled lane offset within a 1KB fragment
    const int aoff = ((lane >> 4) * 256 + r16 * 16) ^ ((lane >> 4) << 5);

    // W fragment base: + kb*16384 + (ks*4+ni)*512
    const __bf16* wbase = wpk + ((size_t)(wid * 8) << 9) + lane * 8;

    f32x4  acc[5][4] = {};
    bf16x8 aR0[3], aR1[3];                 // A slots: even steps / odd steps
    bf16x8 wA[8], wB[8];

    __syncthreads();                       // idx table ready

    // prologue: gather A(0)->aR0, A(1)->aR1 (both kn=0), W(0)->wA
    {
        const int iv0 = idx_lds[alt_[0] * IDXS];
        const int iv1 = idx_lds[alt_[1] * IDXS];
        aR0[0] = *(const bf16x8*)(xb + abase_[0] + (((size_t)iv0) << 8) + goff_[0]);
        aR0[1] = *(const bf16x8*)(xb + abase_[1] + (((size_t)iv1) << 8) + goff_[1]);
        aR1[0] = *(const bf16x8*)(xb + abase_[0] + (((size_t)iv0) << 8) + 64 + goff_[0]);
        aR1[1] = *(const bf16x8*)(xb + abase_[1] + (((size_t)iv1) << 8) + 64 + goff_[1]);
        if (j2) {
            const int iv2 = idx_lds[alt_[2] * IDXS];
            aR0[2] = *(const bf16x8*)(xb + abase_[2] + (((size_t)iv2) << 8) + goff_[2]);
            aR1[2] = *(const bf16x8*)(xb + abase_[2] + (((size_t)iv2) << 8) + 64 + goff_[2]);
        }
#pragma unroll
        for (int j = 0; j < 8; ++j)
            wA[j] = *(const bf16x8*)(wbase + j * 512);
    }

// step S: ds_write AR (gathered at S-2); prefetch A(S+2)->AR, W(S+1)->WNXT.
#define STEP(S, AR, WCUR, WNXT, PFA, PFW)                                       \
    {                                                                           \
        char* db = (char*)&Alds[(S) & 1][0];                                    \
        *(bf16x8*)(db + dsb_[0]) = AR[0];                                       \
        *(bf16x8*)(db + dsb_[1]) = AR[1];                                       \
        if (j2) *(bf16x8*)(db + dsb_[2]) = AR[2];                               \
        BARRIER();                                                              \
        if (PFA) {  /* gather A(S+2) */                                         \
            const int T   = (S) + 2;                                            \
            const int kn  = T >> 2;                                             \
            const int iob = (T & 3) << 6;                                       \
            const int iv0 = idx_lds[alt_[0] * IDXS + kn];                       \
            const int iv1 = idx_lds[alt_[1] * IDXS + kn];                       \
            AR[0] = *(const bf16x8*)(xb + abase_[0] + (((size_t)iv0) << 8) + iob + goff_[0]); \
            AR[1] = *(const bf16x8*)(xb + abase_[1] + (((size_t)iv1) << 8) + iob + goff_[1]); \
            if (j2) {                                                           \
                const int iv2 = idx_lds[alt_[2] * IDXS + kn];                   \
                AR[2] = *(const bf16x8*)(xb + abase_[2] + (((size_t)iv2) << 8) + iob + goff_[2]); \
            }                                                                   \
        }                                                                       \
        if (PFW) {  /* W(S+1) */                                                \
            const __bf16* wq = wbase + ((size_t)((S) + 1)) * 16384;             \
            _Pragma("unroll")                                                   \
            for (int j = 0; j < 8; ++j)                                         \
                WNXT[j] = *(const bf16x8*)(wq + j * 512);                       \
        }                                                                       \
        __builtin_amdgcn_s_setprio(1);                                          \
        _Pragma("unroll")                                                       \
        for (int ks = 0; ks < 2; ++ks) {                                        \
            bf16x8 af[5];                                                       \
            _Pragma("unroll")                                                   \
            for (int mi = 0; mi < 5; ++mi)                                      \
                af[mi] = *(const bf16x8*)(db + (mi * 2 + ks) * 1024 + aoff);    \
            _Pragma("unroll")                                                   \
            for (int mi = 0; mi < 5; ++mi)                                      \
                _Pragma("unroll")                                               \
                for (int ni = 0; ni < 4; ++ni)                                  \
                    acc[mi][ni] = __builtin_amdgcn_mfma_f32_16x16x32_bf16(      \
                        af[mi], WCUR[ks * 4 + ni], acc[mi][ni], 0, 0, 0);       \
        }                                                                       \
        __builtin_amdgcn_s_setprio(0);                                          \
    }

    // steps 0..61: full pipeline (step 61 gathers A(63), last needed)
    for (int s2 = 0; s2 < 31; ++s2) {
        STEP(2 * s2,     aR0, wA, wB, true, true)
        STEP(2 * s2 + 1, aR1, wB, wA, true, true)
    }
    // tail: steps 62, 63 — no A prefetch (A(62),A(63) already in regs)
    STEP(62, aR0, wA, wB, false, true)
    STEP(63, aR1, wB, wA, false, false)
#undef STEP

    // ---- epilogue: C/D layout col=lane&15, row=(lane>>4)*4+reg ----
    float bv[4];
#pragma unroll
    for (int ni = 0; ni < 4; ++ni)
        bv[ni] = bias[wid * 64 + ni * 16 + r16];
#pragma unroll
    for (int mi = 0; mi < 5; ++mi) {
#pragma unroll
        for (int rr = 0; rr < 4; ++rr) {
            const int r  = mi * 16 + q * 4 + rr;   // 0..79
            const int ab = r / TL;
            const int al = r % TL;
            float* dst = out + (((size_t)(ab * Ldim + l0 + al)) << 8) + wid * 64 + r16;
#pragma unroll
            for (int ni = 0; ni < 4; ++ni)
                dst[ni * 16] = acc[mi][ni][rr] + bv[ni];
        }
    }
}

// ---------------- fallback (no-ws path) ----------------
#define FTL 32
#define FBN 128
#define FLDA 72
__global__ __launch_bounds__(256)
void piconv_fallback(const float* __restrict__ x,
                     const int* __restrict__ idxT,
                     const float* __restrict__ mask,
                     const float* __restrict__ bias,
                     float* __restrict__ out)
{
    __shared__ __bf16 Alds[128 * FLDA];
    __shared__ __bf16 Wlds[FBN * FLDA];
    const int t  = threadIdx.x;
    const int l0 = blockIdx.x * FTL;
    const int n0 = blockIdx.y * FBN;
    const int lane = t & 63;
    const int wid  = t >> 6;
    const int wm   = wid >> 1;
    const int wn   = wid & 1;
    const int q    = lane >> 4;
    const int r16  = lane & 15;
    f32x4 acc[4][4] = {};
    const int am    = t >> 1;
    const int ahalf = t & 1;
    const int alt   = am & 31;
    const int abb   = am >> 5;
    const int al    = l0 + alt;
    const bool avalid = (al < Ldim);
    for (int kb = 0; kb < 64; ++kb) {
        {
            const int ksl = kb >> 2;
            const int i0  = ((kb & 3) << 6) + (ahalf << 5);
            const int idx = avalid ? idxT[al * Kdim + ksl] : 0;
            const float* src = x + (((size_t)(abb * Ldim + idx)) << 8) + i0;
#pragma unroll
            for (int j = 0; j < 4; ++j) {
                const float4 f0 = *(const float4*)(src + j * 8);
                const float4 f1 = *(const float4*)(src + j * 8 + 4);
                bf16x8 v;
                v[0] = (__bf16)f0.x; v[1] = (__bf16)f0.y; v[2] = (__bf16)f0.z; v[3] = (__bf16)f0.w;
                v[4] = (__bf16)f1.x; v[5] = (__bf16)f1.y; v[6] = (__bf16)f1.z; v[7] = (__bf16)f1.w;
                *(bf16x8*)&Alds[am * FLDA + (ahalf << 5) + j * 8] = v;
            }
        }
        {
#pragma unroll
            for (int it = 0; it < 4; ++it) {
                const int pair = t + it * 256;
                const int n    = pair & 127;
                const int g    = pair >> 7;
                const float* src = mask + (((size_t)(kb * 64 + g * 8)) << 8) + n0 + n;
                bf16x8 v;
#pragma unroll
                for (int j = 0; j < 8; ++j)
                    v[j] = (__bf16)src[(size_t)j << 8];
                *(bf16x8*)&Wlds[n * FLDA + g * 8] = v;
            }
        }
        __syncthreads();
#pragma unroll
        for (int ks = 0; ks < 2; ++ks) {
            bf16x8 af[4], bfr[4];
#pragma unroll
            for (int mi = 0; mi < 4; ++mi)
                af[mi] = *(bf16x8*)&Alds[(wm * 64 + mi * 16 + r16) * FLDA + ks * 32 + q * 8];
#pragma unroll
            for (int ni = 0; ni < 4; ++ni)
                bfr[ni] = *(bf16x8*)&Wlds[(wn * 64 + ni * 16 + r16) * FLDA + ks * 32 + q * 8];
#pragma unroll
            for (int mi = 0; mi < 4; ++mi)
#pragma unroll
                for (int ni = 0; ni < 4; ++ni)
                    acc[mi][ni] = __builtin_amdgcn_mfma_f32_16x16x32_bf16(
                        af[mi], bfr[ni], acc[mi][ni], 0, 0, 0);
        }
        __syncthreads();
    }
    float bv[4];
#pragma unroll
    for (int ni = 0; ni < 4; ++ni)
        bv[ni] = bias[n0 + wn * 64 + ni * 16 + r16];
#pragma unroll
    for (int mi = 0; mi < 4; ++mi) {
        const int mrow = wm * 64 + mi * 16 + q * 4;
#pragma unroll
        for (int rr = 0; rr < 4; ++rr) {
            const int m  = mrow + rr;
            const int lt = m & 31;
            const int bb = m >> 5;
            const int l  = l0 + lt;
            if (l < Ldim) {
                float* dst = out + (((size_t)(bb * Ldim + l)) << 8) + n0 + wn * 64 + r16;
#pragma unroll
                for (int ni = 0; ni < 4; ++ni)
                    dst[ni * 16] = acc[mi][ni][rr] + bv[ni];
            }
        }
    }
}

extern "C" void kernel_launch(void* const* d_in, const int* in_sizes, int n_in,
                              void* d_out, int out_size, void* d_ws, size_t ws_size,
                              hipStream_t stream) {
    const float* x    = (const float*)d_in[0];
    const int*   idx  = (const int*)d_in[1];
    const float* mask = (const float*)d_in[2];
    const float* bias = (const float*)d_in[3];
    float* out = (float*)d_out;

    const size_t xb_bytes = (size_t)Bdim * Ldim * Idim * 2;   // 20,480,000
    const size_t wp_bytes = (size_t)Kdim * Idim * Odim * 2;   //  2,097,152

    if (ws_size >= xb_bytes + wp_bytes) {
        __bf16* xb  = (__bf16*)d_ws;
        __bf16* wpk = (__bf16*)((char*)d_ws + xb_bytes);
        // 2500 x-convert blocks (2500*256*16 = 10,240,000 floats, exact) + 512 pack blocks
        prepack<<<2500 + 512, 256, 0, stream>>>(x, mask, xb, wpk);
        piconv_gemm<<<Ldim / TL, 256, 0, stream>>>(xb, idx, wpk, bias, out);
    } else {
        dim3 grid((Ldim + FTL - 1) / FTL, Odim / FBN, 1);
        piconv_fallback<<<grid, 256, 0, stream>>>(x, idx, mask, bias, out);
    }
}